// Round 7
// baseline (243.893 us; speedup 1.0000x reference)
//
#include <hip/hip_runtime.h>
#include <math.h>

// Problem constants: L=4096, B=4, D=1024, N=16
#define D_SZ 1024
#define CH 4096          // B*D channels
#define ROW 4096         // x stride between consecutive l (floats)
#define C_CHUNKS 128
#define LC 32            // L / C_CHUNKS
#define SQ_LC 5          // log2(LC)

// ---------------------------------------------------------------------------
// Load 32 consecutive floats (params for channels d0, d0+1) as float4s.
// Params layout: (D, N, 1) -> d*16+n.
// ---------------------------------------------------------------------------
__device__ __forceinline__ void load32(const float* __restrict__ p, int d0, float v[32]) {
    const float4* p4 = (const float4*)(p + (size_t)d0 * 16);
#pragma unroll
    for (int r = 0; r < 8; ++r) {
        float4 t = p4[r];
        v[4*r+0] = t.x; v[4*r+1] = t.y; v[4*r+2] = t.z; v[4*r+3] = t.w;
    }
}

// q/w for channel pair (d0, d0+1): q[0..15]=d0 modes, q[16..31]=d0+1 modes.
__device__ __forceinline__ void compute_qw2(const float* __restrict__ delta,
                                            const float* __restrict__ alpha,
                                            const float* __restrict__ beta,
                                            const float* __restrict__ gamma,
                                            int d0, float q[32], float w[32]) {
    float dl[32], al[32], bt[32], gm[32];
    load32(delta, d0, dl); load32(alpha, d0, al);
    load32(beta, d0, bt);  load32(gamma, d0, gm);
#pragma unroll
    for (int n = 0; n < 32; ++n) {
        float p  = 1.0f / (1.0f + __expf(-dl[n]));
        float sa = 1.0f / (1.0f + __expf(-al[n]));
        q[n] = 1.0f - p * sa;
        w[n] = p * bt[n] * gm[n] * 0.25f;   // scale = 1/sqrt(16)
    }
}

// 4-wide float2 load group; two groups ping-pong = 8 loads (64B/lane) in flight
__device__ __forceinline__ void loadg2(const float* __restrict__ xp, int g, float2 v[4]) {
#pragma unroll
    for (int u = 0; u < 4; ++u)
        v[u] = *(const float2*)(xp + (size_t)(g * 4 + u) * ROW);
}

__device__ __forceinline__ void compg2(float h[32], const float q[32], const float2 v[4]) {
#pragma unroll
    for (int u = 0; u < 4; ++u) {
        float x0 = v[u].x, x1 = v[u].y;
#pragma unroll
        for (int n = 0; n < 16; ++n) h[n]      = fmaf(q[n],      h[n],      x0);
#pragma unroll
        for (int n = 0; n < 16; ++n) h[16 + n] = fmaf(q[16 + n], h[16 + n], x1);
    }
}

// ---------------------------------------------------------------------------
// Phase 1: chunk-local end state (h from 0). S[(j*CH + c)*16 + n].
// Thread owns channels c0, c0+1 -> S write is 128B contiguous.
// Grid: (cgrp fastest, j slow) so concurrent blocks sweep contiguous x rows.
// ---------------------------------------------------------------------------
__global__ __launch_bounds__(256, 4) void k_phase1(const float* __restrict__ x,
    float* __restrict__ S,
    const float* __restrict__ delta, const float* __restrict__ alpha,
    const float* __restrict__ beta, const float* __restrict__ gamma) {
    int t  = threadIdx.x;
    int j  = blockIdx.y;                       // chunk
    int c0 = blockIdx.x * 512 + 2 * t;         // even channel
    int d0 = c0 & (D_SZ - 1);
    float q[32], w[32];
    compute_qw2(delta, alpha, beta, gamma, d0, q, w);   // w dead in p1 -> DCE
    float h[32];
#pragma unroll
    for (int n = 0; n < 32; ++n) h[n] = 0.0f;
    const float* xp = x + (size_t)j * LC * ROW + c0;
    float2 xa[4], xb[4];
    loadg2(xp, 0, xa);
    loadg2(xp, 1, xb); compg2(h, q, xa);
    loadg2(xp, 2, xa); compg2(h, q, xb);
    loadg2(xp, 3, xb); compg2(h, q, xa);
    loadg2(xp, 4, xa); compg2(h, q, xb);
    loadg2(xp, 5, xb); compg2(h, q, xa);
    loadg2(xp, 6, xa); compg2(h, q, xb);
    loadg2(xp, 7, xb); compg2(h, q, xa);
    compg2(h, q, xb);
    float4* Sp = (float4*)(S + ((size_t)j * CH + c0) * 16);
#pragma unroll
    for (int r = 0; r < 8; ++r)
        Sp[r] = make_float4(h[4*r], h[4*r+1], h[4*r+2], h[4*r+3]);
}

// ---------------------------------------------------------------------------
// Phase 2: one wave per channel; lane handles chunks {2i, 2i+1} (affine pair
// composition), Kogge-Stone over 64 lanes, rewrite S with per-chunk carry-IN.
// ---------------------------------------------------------------------------
__global__ __launch_bounds__(256) void k_phase2(float* __restrict__ S,
    const float* __restrict__ delta, const float* __restrict__ alpha) {
    int lane = threadIdx.x & 63;
    int wv   = threadIdx.x >> 6;            // 0..3
    int c    = blockIdx.x * 4 + wv;         // channel
    int d    = c & (D_SZ - 1);
    const float4* d4 = (const float4*)(delta + (size_t)d * 16);
    const float4* a4 = (const float4*)(alpha + (size_t)d * 16);
    float A[16], pw[16];
#pragma unroll
    for (int r = 0; r < 4; ++r) {
        float4 td = d4[r], ta = a4[r];
        float dls[4] = {td.x, td.y, td.z, td.w};
        float als[4] = {ta.x, ta.y, ta.z, ta.w};
#pragma unroll
        for (int k = 0; k < 4; ++k) {
            float p  = 1.0f / (1.0f + __expf(-dls[k]));
            float sa = 1.0f / (1.0f + __expf(-als[k]));
            float qn = 1.0f - p * sa;
#pragma unroll
            for (int tq = 0; tq < SQ_LC; ++tq) qn *= qn;   // q^LC
            A[4*r+k]  = qn;
            pw[4*r+k] = qn * qn;                           // q^(2*LC)
        }
    }
    float4* Spa = (float4*)(S + ((size_t)(2 * lane)     * CH + c) * 16);
    float4* Spb = (float4*)(S + ((size_t)(2 * lane + 1) * CH + c) * 16);
    float sa16[16], sb16[16];
#pragma unroll
    for (int r = 0; r < 4; ++r) {
        float4 ta = Spa[r], tb = Spb[r];
        sa16[4*r] = ta.x; sa16[4*r+1] = ta.y; sa16[4*r+2] = ta.z; sa16[4*r+3] = ta.w;
        sb16[4*r] = tb.x; sb16[4*r+1] = tb.y; sb16[4*r+2] = tb.z; sb16[4*r+3] = tb.w;
    }
    float hh[16];
#pragma unroll
    for (int n = 0; n < 16; ++n) hh[n] = fmaf(A[n], sa16[n], sb16[n]);  // pair composite
#pragma unroll
    for (int k = 1; k <= 32; k <<= 1) {
        float prev[16];
#pragma unroll
        for (int n = 0; n < 16; ++n) prev[n] = __shfl_up(hh[n], (unsigned)k, 64);
#pragma unroll
        for (int n = 0; n < 16; ++n) hh[n] = (lane >= k) ? fmaf(pw[n], prev[n], hh[n]) : hh[n];
#pragma unroll
        for (int n = 0; n < 16; ++n) pw[n] *= pw[n];
    }
    float Hb[16];                                    // state before chunk 2i
#pragma unroll
    for (int n = 0; n < 16; ++n) {
        float tv = __shfl_up(hh[n], 1u, 64);
        Hb[n] = (lane == 0) ? 0.0f : tv;
    }
    // carry-in(2i) = Hb; carry-in(2i+1) = A*Hb + S_2i
#pragma unroll
    for (int r = 0; r < 4; ++r) {
        Spa[r] = make_float4(Hb[4*r], Hb[4*r+1], Hb[4*r+2], Hb[4*r+3]);
        Spb[r] = make_float4(fmaf(A[4*r],   Hb[4*r],   sa16[4*r]),
                             fmaf(A[4*r+1], Hb[4*r+1], sa16[4*r+1]),
                             fmaf(A[4*r+2], Hb[4*r+2], sa16[4*r+2]),
                             fmaf(A[4*r+3], Hb[4*r+3], sa16[4*r+3]));
    }
}

// ---------------------------------------------------------------------------
// Phase 3: recurrence seeded with carry-in; out = silu(sum_n w_n h_n + x*omega)
// ---------------------------------------------------------------------------
__device__ __forceinline__ void comp_store2(float h[32], const float q[32], const float w[32],
                                            float om0, float om1, const float2 v[4],
                                            float* __restrict__ outp, int g) {
#pragma unroll
    for (int u = 0; u < 4; ++u) {
        float x0 = v[u].x, x1 = v[u].y;
        float ya = 0.0f, yb = 0.0f, yc = 0.0f, yd = 0.0f;
#pragma unroll
        for (int n = 0; n < 16; n += 2) {
            h[n]   = fmaf(q[n],   h[n],   x0); ya = fmaf(w[n],   h[n],   ya);
            h[n+1] = fmaf(q[n+1], h[n+1], x0); yb = fmaf(w[n+1], h[n+1], yb);
        }
#pragma unroll
        for (int n = 16; n < 32; n += 2) {
            h[n]   = fmaf(q[n],   h[n],   x1); yc = fmaf(w[n],   h[n],   yc);
            h[n+1] = fmaf(q[n+1], h[n+1], x1); yd = fmaf(w[n+1], h[n+1], yd);
        }
        float z0 = (ya + yb) + x0 * om0;
        float z1 = (yc + yd) + x1 * om1;
        float2 o;
        o.x = z0 / (1.0f + __expf(-z0));
        o.y = z1 / (1.0f + __expf(-z1));
        *(float2*)(outp + (size_t)(g * 4 + u) * ROW) = o;
    }
}

__global__ __launch_bounds__(256, 4) void k_phase3(const float* __restrict__ x,
    const float* __restrict__ S, float* __restrict__ out,
    const float* __restrict__ delta, const float* __restrict__ alpha,
    const float* __restrict__ beta, const float* __restrict__ gamma,
    const float* __restrict__ omega) {
    int t  = threadIdx.x;
    int j  = blockIdx.y;
    int c0 = blockIdx.x * 512 + 2 * t;
    int d0 = c0 & (D_SZ - 1);
    float q[32], w[32];
    compute_qw2(delta, alpha, beta, gamma, d0, q, w);
    float2 omv = *(const float2*)(omega + d0);
    float h[32];
    const float4* Sp = (const float4*)(S + ((size_t)j * CH + c0) * 16);
#pragma unroll
    for (int r = 0; r < 8; ++r) {
        float4 tv = Sp[r];
        h[4*r] = tv.x; h[4*r+1] = tv.y; h[4*r+2] = tv.z; h[4*r+3] = tv.w;
    }
    const float* xp = x + (size_t)j * LC * ROW + c0;
    float* outp = out + (size_t)j * LC * ROW + c0;
    float2 xa[4], xb[4];
    loadg2(xp, 0, xa);
    loadg2(xp, 1, xb); comp_store2(h, q, w, omv.x, omv.y, xa, outp, 0);
    loadg2(xp, 2, xa); comp_store2(h, q, w, omv.x, omv.y, xb, outp, 1);
    loadg2(xp, 3, xb); comp_store2(h, q, w, omv.x, omv.y, xa, outp, 2);
    loadg2(xp, 4, xa); comp_store2(h, q, w, omv.x, omv.y, xb, outp, 3);
    loadg2(xp, 5, xb); comp_store2(h, q, w, omv.x, omv.y, xa, outp, 4);
    loadg2(xp, 6, xa); comp_store2(h, q, w, omv.x, omv.y, xb, outp, 5);
    loadg2(xp, 7, xb); comp_store2(h, q, w, omv.x, omv.y, xa, outp, 6);
    comp_store2(h, q, w, omv.x, omv.y, xb, outp, 7);
}

// ---------------------------------------------------------------------------
extern "C" void kernel_launch(void* const* d_in, const int* in_sizes, int n_in,
                              void* d_out, int out_size, void* d_ws, size_t ws_size,
                              hipStream_t stream) {
    const float* x     = (const float*)d_in[0];
    const float* delta = (const float*)d_in[1];
    const float* alpha = (const float*)d_in[2];
    const float* beta  = (const float*)d_in[3];
    const float* gamma = (const float*)d_in[4];
    const float* omega = (const float*)d_in[5];
    float* out = (float*)d_out;
    float* S   = (float*)d_ws;   // 128*4096*16*4B = 33.5 MB

    // cgrp fastest (x), j slow (y): concurrent blocks sweep contiguous x rows
    dim3 grid13(CH / 512, C_CHUNKS);   // (8, 128) = 1024 blocks
    k_phase1<<<grid13, 256, 0, stream>>>(x, S, delta, alpha, beta, gamma);
    k_phase2<<<CH / 4, 256, 0, stream>>>(S, delta, alpha);
    k_phase3<<<grid13, 256, 0, stream>>>(x, S, out, delta, alpha, beta, gamma, omega);
}

// Round 8
// 187.267 us; speedup vs baseline: 1.3024x; 1.3024x over previous
//
#include <hip/hip_runtime.h>
#include <math.h>

// Problem constants: L=4096, B=4, D=1024, N=16
#define D_SZ 1024
#define CH 4096          // B*D channels
#define ROW 4096         // x stride between consecutive l (floats)
#define C_CHUNKS 128
#define LC 32            // L / C_CHUNKS
#define SQ_LC 5          // log2(LC)

// Mode-split design: a thread PAIR owns one channel; lane parity m owns modes
// [8m, 8m+8). Live state per thread ~50 floats -> fits the compiler's 64-VGPR
// target with zero spill (R7 failure mode: 120 live @ 64 VGPR -> scratch).

// Load 8 mode-params (two float4s) for channel d, mode-half m.
__device__ __forceinline__ void load8(const float* __restrict__ p, int d, int m, float v[8]) {
    const float4* p4 = (const float4*)(p + (size_t)d * 16 + m * 8);
    float4 a = p4[0], b = p4[1];
    v[0] = a.x; v[1] = a.y; v[2] = a.z; v[3] = a.w;
    v[4] = b.x; v[5] = b.y; v[6] = b.z; v[7] = b.w;
}

__device__ __forceinline__ void compute_qw8(const float* __restrict__ delta,
                                            const float* __restrict__ alpha,
                                            const float* __restrict__ beta,
                                            const float* __restrict__ gamma,
                                            int d, int m, float q[8], float w[8]) {
    float dl[8], al[8], bt[8], gm[8];
    load8(delta, d, m, dl); load8(alpha, d, m, al);
    load8(beta, d, m, bt);  load8(gamma, d, m, gm);
#pragma unroll
    for (int n = 0; n < 8; ++n) {
        float p  = 1.0f / (1.0f + __expf(-dl[n]));
        float sa = 1.0f / (1.0f + __expf(-al[n]));
        q[n] = 1.0f - p * sa;
        w[n] = p * bt[n] * gm[n] * 0.25f;   // scale = 1/sqrt(16)
    }
}

// 8-wide load group; two groups ping-pong = 16 loads in flight per lane.
// Pair lanes load the same address (coalescer merges; 128B/wave-instr dense).
__device__ __forceinline__ void loadg(const float* __restrict__ xp, int g, float v[8]) {
#pragma unroll
    for (int u = 0; u < 8; ++u) v[u] = xp[(size_t)(g * 8 + u) * ROW];
}

__device__ __forceinline__ void compg8(float h[8], const float q[8], const float v[8]) {
#pragma unroll
    for (int u = 0; u < 8; ++u) {
        float xu = v[u];
#pragma unroll
        for (int n = 0; n < 8; ++n) h[n] = fmaf(q[n], h[n], xu);
    }
}

// ---------------------------------------------------------------------------
// Phase 1: chunk-local end state (h from 0). S[(j*CH + c)*16 + n].
// Pair writes its channel's 16 states as 4 contiguous float4s (2 per lane).
// ---------------------------------------------------------------------------
__global__ __launch_bounds__(256) void k_phase1(const float* __restrict__ x,
    float* __restrict__ S,
    const float* __restrict__ delta, const float* __restrict__ alpha,
    const float* __restrict__ beta, const float* __restrict__ gamma) {
    int tid = threadIdx.x;
    int j   = blockIdx.x;                    // chunk
    int pr  = tid >> 1;                      // pair index 0..127
    int m   = tid & 1;                       // mode half
    int c   = blockIdx.y * 128 + pr;         // channel
    int d   = c & (D_SZ - 1);
    float q[8], w[8];
    compute_qw8(delta, alpha, beta, gamma, d, m, q, w);  // w dead -> DCE
    float h[8];
#pragma unroll
    for (int n = 0; n < 8; ++n) h[n] = 0.0f;
    const float* xp = x + (size_t)j * LC * ROW + c;
    float xa[8], xb[8];
    loadg(xp, 0, xa);
    loadg(xp, 1, xb); compg8(h, q, xa);
    loadg(xp, 2, xa); compg8(h, q, xb);
    loadg(xp, 3, xb); compg8(h, q, xa);
    compg8(h, q, xb);
    float4* Sp = (float4*)(S + ((size_t)j * CH + c) * 16 + m * 8);
    Sp[0] = make_float4(h[0], h[1], h[2], h[3]);
    Sp[1] = make_float4(h[4], h[5], h[6], h[7]);
}

// ---------------------------------------------------------------------------
// Phase 2: wave handles 8 modes of ONE channel; lane = chunk-pair {2i,2i+1}.
// Affine pair composition then Kogge-Stone; rewrite S with per-chunk carry-IN.
// ---------------------------------------------------------------------------
__global__ __launch_bounds__(256) void k_phase2(float* __restrict__ S,
    const float* __restrict__ delta, const float* __restrict__ alpha) {
    int tid  = threadIdx.x;
    int wv   = tid >> 6;                    // 0..3
    int lane = tid & 63;
    int c    = blockIdx.x * 2 + (wv >> 1);  // channel
    int mo   = (wv & 1);                    // mode half
    int d    = c & (D_SZ - 1);
    float dl[8], al[8];
    load8(delta, d, mo, dl); load8(alpha, d, mo, al);
    float A[8], pw[8];
#pragma unroll
    for (int n = 0; n < 8; ++n) {
        float p  = 1.0f / (1.0f + __expf(-dl[n]));
        float sa = 1.0f / (1.0f + __expf(-al[n]));
        float qn = 1.0f - p * sa;
#pragma unroll
        for (int t = 0; t < SQ_LC; ++t) qn *= qn;    // q^LC
        A[n]  = qn;
        pw[n] = qn * qn;                             // q^(2*LC)
    }
    float4* Spa = (float4*)(S + ((size_t)(2 * lane)     * CH + c) * 16 + mo * 8);
    float4* Spb = (float4*)(S + ((size_t)(2 * lane + 1) * CH + c) * 16 + mo * 8);
    float sa8[8], sb8[8];
    {
        float4 a0 = Spa[0], a1 = Spa[1], b0 = Spb[0], b1 = Spb[1];
        sa8[0]=a0.x; sa8[1]=a0.y; sa8[2]=a0.z; sa8[3]=a0.w;
        sa8[4]=a1.x; sa8[5]=a1.y; sa8[6]=a1.z; sa8[7]=a1.w;
        sb8[0]=b0.x; sb8[1]=b0.y; sb8[2]=b0.z; sb8[3]=b0.w;
        sb8[4]=b1.x; sb8[5]=b1.y; sb8[6]=b1.z; sb8[7]=b1.w;
    }
    float hh[8];
#pragma unroll
    for (int n = 0; n < 8; ++n) hh[n] = fmaf(A[n], sa8[n], sb8[n]);  // pair composite
#pragma unroll
    for (int k = 1; k <= 32; k <<= 1) {
        float prev[8];
#pragma unroll
        for (int n = 0; n < 8; ++n) prev[n] = __shfl_up(hh[n], (unsigned)k, 64);
#pragma unroll
        for (int n = 0; n < 8; ++n) hh[n] = (lane >= k) ? fmaf(pw[n], prev[n], hh[n]) : hh[n];
#pragma unroll
        for (int n = 0; n < 8; ++n) pw[n] *= pw[n];
    }
    float Hb[8];                                     // state before chunk 2i
#pragma unroll
    for (int n = 0; n < 8; ++n) {
        float tv = __shfl_up(hh[n], 1u, 64);
        Hb[n] = (lane == 0) ? 0.0f : tv;
    }
    // carry-in(2i) = Hb; carry-in(2i+1) = A*Hb + S_2i
    Spa[0] = make_float4(Hb[0], Hb[1], Hb[2], Hb[3]);
    Spa[1] = make_float4(Hb[4], Hb[5], Hb[6], Hb[7]);
    Spb[0] = make_float4(fmaf(A[0], Hb[0], sa8[0]), fmaf(A[1], Hb[1], sa8[1]),
                         fmaf(A[2], Hb[2], sa8[2]), fmaf(A[3], Hb[3], sa8[3]));
    Spb[1] = make_float4(fmaf(A[4], Hb[4], sa8[4]), fmaf(A[5], Hb[5], sa8[5]),
                         fmaf(A[6], Hb[6], sa8[6]), fmaf(A[7], Hb[7], sa8[7]));
}

// ---------------------------------------------------------------------------
// Phase 3: recurrence seeded with carry-in. Pair combines mode-half partial
// sums via shfl_xor(1); even lane stores (32 even lanes = 128B dense line).
// ---------------------------------------------------------------------------
__device__ __forceinline__ void comp_store8(float h[8], const float q[8], const float w[8],
                                            float om, int m, const float v[8],
                                            float* __restrict__ outp, int g) {
#pragma unroll
    for (int u = 0; u < 8; ++u) {
        float xu = v[u];
        float y0 = 0.0f, y1 = 0.0f;
#pragma unroll
        for (int n = 0; n < 8; n += 2) {
            h[n]   = fmaf(q[n],   h[n],   xu); y0 = fmaf(w[n],   h[n],   y0);
            h[n+1] = fmaf(q[n+1], h[n+1], xu); y1 = fmaf(w[n+1], h[n+1], y1);
        }
        float y  = y0 + y1;
        float yo = __shfl_xor(y, 1, 64);          // partner's mode-half
        float z  = y + yo + xu * om;
        float r  = z / (1.0f + __expf(-z));       // silu
        if (m == 0) outp[(size_t)(g * 8 + u) * ROW] = r;
    }
}

__global__ __launch_bounds__(256) void k_phase3(const float* __restrict__ x,
    const float* __restrict__ S, float* __restrict__ out,
    const float* __restrict__ delta, const float* __restrict__ alpha,
    const float* __restrict__ beta, const float* __restrict__ gamma,
    const float* __restrict__ omega) {
    int tid = threadIdx.x;
    int j   = blockIdx.x;
    int pr  = tid >> 1;
    int m   = tid & 1;
    int c   = blockIdx.y * 128 + pr;
    int d   = c & (D_SZ - 1);
    float q[8], w[8];
    compute_qw8(delta, alpha, beta, gamma, d, m, q, w);
    float om = omega[d];
    float h[8];
    {
        const float4* Sp = (const float4*)(S + ((size_t)j * CH + c) * 16 + m * 8);
        float4 a = Sp[0], b = Sp[1];
        h[0]=a.x; h[1]=a.y; h[2]=a.z; h[3]=a.w;
        h[4]=b.x; h[5]=b.y; h[6]=b.z; h[7]=b.w;
    }
    const float* xp  = x   + (size_t)j * LC * ROW + c;
    float*       outp = out + (size_t)j * LC * ROW + c;
    float xa[8], xb[8];
    loadg(xp, 0, xa);
    loadg(xp, 1, xb); comp_store8(h, q, w, om, m, xa, outp, 0);
    loadg(xp, 2, xa); comp_store8(h, q, w, om, m, xb, outp, 1);
    loadg(xp, 3, xb); comp_store8(h, q, w, om, m, xa, outp, 2);
    comp_store8(h, q, w, om, m, xb, outp, 3);
}

// ---------------------------------------------------------------------------
extern "C" void kernel_launch(void* const* d_in, const int* in_sizes, int n_in,
                              void* d_out, int out_size, void* d_ws, size_t ws_size,
                              hipStream_t stream) {
    const float* x     = (const float*)d_in[0];
    const float* delta = (const float*)d_in[1];
    const float* alpha = (const float*)d_in[2];
    const float* beta  = (const float*)d_in[3];
    const float* gamma = (const float*)d_in[4];
    const float* omega = (const float*)d_in[5];
    float* out = (float*)d_out;
    float* S   = (float*)d_ws;   // 128*4096*16*4B = 33.5 MB

    // j fastest (R6 order), 128 channels per block (thread pairs)
    dim3 grid13(C_CHUNKS, CH / 128);   // (128, 32) = 4096 blocks
    k_phase1<<<grid13, 256, 0, stream>>>(x, S, delta, alpha, beta, gamma);
    k_phase2<<<CH / 2, 256, 0, stream>>>(S, delta, alpha);
    k_phase3<<<grid13, 256, 0, stream>>>(x, S, out, delta, alpha, beta, gamma, omega);
}